// Round 6
// baseline (271.536 us; speedup 1.0000x reference)
//
#include <hip/hip_runtime.h>
#include <math.h>

#define BN 32
#define NPTS 2048
#define MPTS 2048
#define ITERS 5
#define LOG2E 1.44269504088896340736f
#define SHIFT_C 14.0f              // log2 headroom so P=2^(C-log2e*d^2) fits f16

typedef _Float16 v8h __attribute__((ext_vector_type(8)));
typedef _Float16 v4h __attribute__((ext_vector_type(4)));
typedef __fp16   f16x2 __attribute__((ext_vector_type(2)));
typedef float    v4f __attribute__((ext_vector_type(4)));

// ws layout (floats):
//  BAR_OFF  [0, 1024)         per-batch barrier counters, 32 dwords (128B) apart
//                             (zeroed by hipMemsetAsync before each launch)
//  PART_OFF [2048, ...)       partial Kabsch sums [ITERS][BN][8][8]
#define BAR_OFF  0
#define PART_OFF 2048

// Closed-form 2x2 Kabsch from summed acc (a8[8]); composes onto (c,s,tx,ty).
__device__ __forceinline__ void kabsch_compose(const float* a8,
                                               float& Tc, float& Ts,
                                               float& Ttx, float& Tty) {
    const float Ssx = a8[0], Ssy = a8[1], Stcx = a8[2], Stcy = a8[3];
    const float Sxx = a8[4], Sxy = a8[5], Syx = a8[6], Syy = a8[7];
    const float invN = 1.0f / (float)NPTS;
    const float csx = Ssx * invN, csy = Ssy * invN;
    const float ctx = Stcx * invN, cty = Stcy * invN;
    const float Hxx = Sxx - Ssx * ctx;
    const float Hxy = Sxy - Ssx * cty;
    const float Hyx = Syx - Ssy * ctx;
    const float Hyy = Syy - Ssy * cty;
    // A = H^T ; R_delta = polar(A) = V U^T
    const float a = Hxx, bb = Hyx, cc = Hxy, d = Hyy;
    const float det = a * d - bb * cc;
    const bool refl = (det < 0.f);
    const float xr = refl ? (a - d) : (a + d);
    const float yr = refl ? (bb + cc) : (cc - bb);
    const float r = fmaxf(sqrtf(xr * xr + yr * yr), 1e-30f);
    const float R00 = xr / r, R10 = yr / r;
    const float R01 = refl ? R10 : -R10;
    const float R11 = refl ? -R00 : R00;
    const float tdx = ctx - (R00 * csx + R01 * csy);
    const float tdy = cty - (R10 * csx + R11 * csy);
    const float cD = R00, sD = R10;      // cos/sin(delta_theta)
    const float nC  = cD * Tc - sD * Ts;
    const float nS  = sD * Tc + cD * Ts;
    const float nTx = cD * Ttx - sD * Tty + tdx;
    const float nTy = sD * Ttx + cD * Tty + tdy;
    Tc = nC; Ts = nS; Ttx = nTx; Tty = nTy;
}

// Per-batch 8-block barrier (R5 post-mortem: the 256-wide single-counter
// barrier cost ~20us/iter — 256 cross-XCD RMWs + 256 spinners on ONE line.
// Only the 8 blocks of one batch exchange data, so sync only those.)
// Monotonic counter per batch on its own 128B line: iter k waits for
// count >= 8*(k+1); no per-iter reset, no reset races. Release-add /
// acquire-load makes the 8 blocks' relaxed partial stores visible.
__device__ __forceinline__ void batch_sync(unsigned* cnt, int tid, unsigned target) {
    __syncthreads();
    if (tid == 0) {
        __hip_atomic_fetch_add(cnt, 1u, __ATOMIC_RELEASE, __HIP_MEMORY_SCOPE_AGENT);
        unsigned v;
        do {
            __builtin_amdgcn_s_sleep(1);
            v = __hip_atomic_load(cnt, __ATOMIC_ACQUIRE, __HIP_MEMORY_SCOPE_AGENT);
        } while (v < target);
    }
    __syncthreads();
}

// ---------------------------------------------------------------------------
// Fused persistent ICP: all 5 soft-assign passes + T updates + final output in
// one kernel, PLAIN launch (coop launch cost ~55-65us of host overhead per
// replay — R1/R2/R5 total-minus-dispatch). Co-residency safety for the spin
// barrier WITHOUT cooperative launch: __launch_bounds__(1024, 8) pins the
// allocator to <=64 VGPR (8 waves/EU budget = 512/8) and LDS is 57.9KB, so
// TWO blocks fit per CU in every resource dimension -> all 256 blocks are
// resident under ANY packing; spins terminate. (The 64-VGPR spill is accepted:
// R1 showed the original 20.5us/pass kernel carried the identical 32.8MB
// write signature, so spill is the known steady state, not the regression.)
// Targets staged ONCE per CU. T chain lives in LDS; Kabsch partials cross
// blocks via agent-scope atomics around the per-batch barrier.
// Per tile: D1 = mfma_16x16x32_f16(a1, B1[nt], 0)   // scores (fp32)
//           P  = pkrtz(exp2(D1))                     // f16; D-layout==B-layout
//           D2 = mfma_16x16x16_f16(a2, P, D2)        // rows 0..2 = den, ax, ay
// ---------------------------------------------------------------------------
__global__ __launch_bounds__(1024, 8)
void icp_fused(const float* __restrict__ source,
               const float* __restrict__ target,
               const float* __restrict__ init_t,
               float* __restrict__ ws,
               float* __restrict__ out) {
    __shared__ v8h A1s[2050];            // 2048 payload + [2048]=const11 [2049]=zero
    __shared__ v8h A2s[516];             // 512 payload + [512]=ones4 [513]=zero
    __shared__ float4 comb[16][4][16];
    __shared__ float red[4][8];
    __shared__ float shT[6];
    __shared__ float pacc[64];
    const int tid = threadIdx.x;
    const int wv  = tid >> 6;
    const int l   = tid & 63;
    const int q   = l >> 4;
    const int col = l & 15;
    const int wq  = wv & 3;              // m-quarter (32 tiles)
    const int rg  = wv >> 2;             // row-group within block (0..3)
    const int b   = blockIdx.x & 31;     // batch
    const int gg  = blockIdx.x >> 5;     // 256-row group (0..7)
    const int g   = gg * 4 + rg;         // 64-row group (0..31)

    unsigned* bar = (unsigned*)(ws + BAR_OFF) + b * 32;   // 128B line per batch

    const _Float16 h0 = (_Float16)0.0f;
    const _Float16 h1 = (_Float16)1.0f;

    // ---- build LDS payloads directly from target (ONCE per CU) ----
    const float2* tg = (const float2*)target + b * MPTS;
#pragma unroll
    for (int i = 0; i < 2; ++i) {
        const int m = tid + i * 1024;
        const float2 k = tg[m];
        const float bm = -LOG2E * fmaf(k.x, k.x, k.y * k.y);
        const _Float16 kxh = (_Float16)k.x;
        const _Float16 kxl = (_Float16)(k.x - (float)kxh);
        const _Float16 kyh = (_Float16)k.y;
        const _Float16 kyl = (_Float16)(k.y - (float)kyh);
        const _Float16 bmh = (_Float16)bm;
        const _Float16 bml = (_Float16)(bm - (float)bmh);
        A1s[m] = (v8h){kxh, kxh, kxl, kyh, kyh, kyl, bmh, bml};
    }
    if (tid < 512) {                     // A2: entry e holds kx/ky of targets 4e..4e+3
        const int e = tid;
        const float2 k0 = tg[e * 4 + 0];
        const float2 k1 = tg[e * 4 + 1];
        const float2 k2 = tg[e * 4 + 2];
        const float2 k3 = tg[e * 4 + 3];
        A2s[e] = (v8h){(_Float16)k0.x, (_Float16)k1.x, (_Float16)k2.x, (_Float16)k3.x,
                       (_Float16)k0.y, (_Float16)k1.y, (_Float16)k2.y, (_Float16)k3.y};
    }
    if (tid == 0) {
        A1s[2048] = (v8h){h1, h1, h0, h0, h0, h0, h0, h0};
        A1s[2049] = (v8h){h0, h0, h0, h0, h0, h0, h0, h0};
        A2s[512]  = (v8h){h1, h1, h1, h1, h0, h0, h0, h0};
        A2s[513]  = (v8h){h0, h0, h0, h0, h0, h0, h0, h0};
        // initial T from init vector
        const float th = init_t[b * 3 + 0];
        const float c = cosf(th), s = sinf(th);
        shT[0] = c; shT[1] = -s; shT[2] = init_t[b * 3 + 1];
        shT[3] = s; shT[4] = c;  shT[5] = init_t[b * 3 + 2];
    }
    __syncthreads();

    // ---- per-lane LDS addressing constants ----
    const char* A1c = (const char*)A1s;
    const char* A2c = (const char*)A2s;
    const int ad1_0 = (q == 0) ? (wq * 512 + col) * 16 : ((q == 1) ? 2048 * 16 : 2049 * 16);
    const int st1   = (q == 0) ? 256 : 0;
    const int ad2_0 = (col == 1) ? (wq * 2048 + q * 16)
                    : (col == 2) ? (wq * 2048 + q * 16 + 8)
                    : ((col == 0) ? 512 * 16 : 513 * 16);
    const int st2   = (col == 1 || col == 2) ? 64 : 0;
    const v4f zero4 = (v4f){0.f, 0.f, 0.f, 0.f};

#pragma unroll 1
    for (int iter = 0; iter < ITERS; ++iter) {
        const float r00 = shT[0], r01 = shT[1], tx = shT[2];
        const float r10 = shT[3], r11 = shT[4], ty = shT[5];

        // ---- B1 frags for this wave's 4 n-tiles ----
        v8h B1[4];
#pragma unroll
        for (int nt = 0; nt < 4; ++nt) {
            const int row = g * 64 + nt * 16 + col;
            const float2 sp = ((const float2*)source)[b * NPTS + row];
            const float sx = fmaf(r00, sp.x, fmaf(r01, sp.y, tx));
            const float sy = fmaf(r10, sp.x, fmaf(r11, sp.y, ty));
            const float qpx = 2.0f * LOG2E * sx;
            const float qpy = 2.0f * LOG2E * sy;
            const float rc  = SHIFT_C - LOG2E * fmaf(sx, sx, sy * sy);
            const _Float16 qpxh = (_Float16)qpx;
            const _Float16 qpxl = (_Float16)(qpx - (float)qpxh);
            const _Float16 qpyh = (_Float16)qpy;
            const _Float16 qpyl = (_Float16)(qpy - (float)qpyh);
            const _Float16 rch  = (_Float16)rc;
            const _Float16 rcl  = (_Float16)(rc - (float)rch);
            v8h f;
            if (q == 0)      f = (v8h){qpxh, qpxl, qpxh, qpyh, qpyl, qpyh, h1, h1};
            else if (q == 1) f = (v8h){rch, rcl, h0, h0, h0, h0, h0, h0};
            else             f = (v8h){h0, h0, h0, h0, h0, h0, h0, h0};
            B1[nt] = f;
        }

        int ad1 = ad1_0;
        int ad2 = ad2_0;

        v4f D2[4];
#pragma unroll
        for (int nt = 0; nt < 4; ++nt) D2[nt] = zero4;

        // ---- fully-unrolled 32-tile pipeline, depth-limited circular bufs ----
        v8h a1w[4];                      // slots (t)&3; load t+2, consume t+1 (D1), t (D2 path)
        v4h a2w[4];
        v4f D1w[2][4];                   // slots (t)&1; produce t+1, consume t
        a1w[0] = *(const v8h*)(A1c + ad1); a2w[0] = *(const v4h*)(A2c + ad2);
        ad1 += st1; ad2 += st2;
        a1w[1] = *(const v8h*)(A1c + ad1); a2w[1] = *(const v4h*)(A2c + ad2);
        ad1 += st1; ad2 += st2;
#pragma unroll
        for (int nt = 0; nt < 4; ++nt)
            D1w[0][nt] = __builtin_amdgcn_mfma_f32_16x16x32_f16(a1w[0], B1[nt], zero4, 0, 0, 0);

#pragma unroll
        for (int t = 0; t < 32; ++t) {
            if (t < 30) {                        // ds prefetch depth 2
                a1w[(t + 2) & 3] = *(const v8h*)(A1c + ad1);
                a2w[(t + 2) & 3] = *(const v4h*)(A2c + ad2);
                ad1 += st1; ad2 += st2;
            }
            if (t < 31) {                        // score tile t+1 ahead of consuming t
#pragma unroll
                for (int nt = 0; nt < 4; ++nt)
                    D1w[(t + 1) & 1][nt] =
                        __builtin_amdgcn_mfma_f32_16x16x32_f16(a1w[(t + 1) & 3], B1[nt], zero4, 0, 0, 0);
            }
            // consume tile t: 16 exps batched, then pack + accumulate
            float e[16];
#pragma unroll
            for (int nt = 0; nt < 4; ++nt)
#pragma unroll
                for (int j = 0; j < 4; ++j)
                    e[nt * 4 + j] = __builtin_amdgcn_exp2f(D1w[t & 1][nt][j]);
#pragma unroll
            for (int nt = 0; nt < 4; ++nt) {
                union { v4h v; f16x2 h[2]; } u;
                u.h[0] = __builtin_amdgcn_cvt_pkrtz(e[nt * 4 + 0], e[nt * 4 + 1]);
                u.h[1] = __builtin_amdgcn_cvt_pkrtz(e[nt * 4 + 2], e[nt * 4 + 3]);
                D2[nt] = __builtin_amdgcn_mfma_f32_16x16x16f16(a2w[t & 3], u.v, D2[nt], 0, 0, 0);
            }
        }

        // ---- combine the 4 m-quarters within each row-group ----
        if (l < 16) {
#pragma unroll
            for (int nt = 0; nt < 4; ++nt)
                comb[wv][nt][col] = make_float4(D2[nt][0], D2[nt][1], D2[nt][2], 0.f);
        }
        __syncthreads();
        float den = 0.f, ax = 0.f, ay = 0.f;
#pragma unroll
        for (int w = 0; w < 4; ++w) {
            const float4 p = comb[rg * 4 + w][q][col];
            den += p.x; ax += p.y; ay += p.z;
        }
        const float tcx = ax / den;
        const float tcy = ay / den;
        const int erow = g * 64 + q * 16 + col;
        const float2 sp = ((const float2*)source)[b * NPTS + erow];
        const float sx = fmaf(r00, sp.x, fmaf(r01, sp.y, tx));
        const float sy = fmaf(r10, sp.x, fmaf(r11, sp.y, ty));
        float v[8] = {sx, sy, tcx, tcy, sx * tcx, sx * tcy, sy * tcx, sy * tcy};
#pragma unroll
        for (int off = 32; off > 0; off >>= 1) {
#pragma unroll
            for (int j = 0; j < 8; ++j) v[j] += __shfl_xor(v[j], off, 64);
        }
        if (l == 0 && wq == 0) {                 // wv = rg*4: one writer per row-group
#pragma unroll
            for (int j = 0; j < 8; ++j) red[rg][j] = v[j];
        }
        __syncthreads();
        if (tid < 8) {                           // block's slot: agent-scope (cross-XCD) stores
            const float vsum = (red[0][tid] + red[1][tid]) + (red[2][tid] + red[3][tid]);
            __hip_atomic_store(ws + PART_OFF + (size_t)iter * BN * 64 + b * 64 + gg * 8 + tid,
                               vsum, __ATOMIC_RELAXED, __HIP_MEMORY_SCOPE_AGENT);
        }

        batch_sync(bar, tid, 8u * (unsigned)(iter + 1));   // this batch's 8 blocks only

        if (tid < 64)                            // load all 8 gg-slots for this batch
            pacc[tid] = __hip_atomic_load(ws + PART_OFF + (size_t)iter * BN * 64 + b * 64 + tid,
                                          __ATOMIC_ACQUIRE, __HIP_MEMORY_SCOPE_AGENT);
        __syncthreads();
        if (tid == 0) {
            float a8[8];
#pragma unroll
            for (int j = 0; j < 8; ++j) {
                float s = 0.f;
#pragma unroll
                for (int s8 = 0; s8 < 8; ++s8) s += pacc[s8 * 8 + j];
                a8[j] = s;
            }
            float Tc = shT[0], Ts = shT[3], Ttx = shT[2], Tty = shT[5];
            kabsch_compose(a8, Tc, Ts, Ttx, Tty);
            shT[0] = Tc; shT[1] = -Ts; shT[2] = Ttx;
            shT[3] = Ts; shT[4] = Tc;  shT[5] = Tty;
            if (iter == ITERS - 1 && gg == 0) {  // one writer block per batch
                out[b * 3 + 0] = atan2f(Ts, Tc);
                out[b * 3 + 1] = Ttx;
                out[b * 3 + 2] = Tty;
            }
        }
        __syncthreads();
    }
}

extern "C" void kernel_launch(void* const* d_in, const int* in_sizes, int n_in,
                              void* d_out, int out_size, void* d_ws, size_t ws_size,
                              hipStream_t stream) {
    const float* source = (const float*)d_in[0];
    const float* target = (const float*)d_in[1];
    const float* initt  = (const float*)d_in[2];
    float* out = (float*)d_out;
    float* ws  = (float*)d_ws;

    // zero the per-batch barrier counters (stream-ordered, graph-capture-safe)
    (void)hipMemsetAsync(ws + BAR_OFF, 0, 32 * 32 * sizeof(float), stream);

    icp_fused<<<dim3(BN * 8), dim3(1024), 0, stream>>>(source, target, initt, ws, out);
}

// Round 8
// 156.067 us; speedup vs baseline: 1.7399x; 1.7399x over previous
//
#include <hip/hip_runtime.h>
#include <math.h>

#define BN 32
#define NPTS 2048
#define MPTS 2048
#define ITERS 5
#define LOG2E 1.44269504088896340736f
#define SHIFT_C 14.0f              // log2 headroom so P=2^(C-log2e*d^2) fits f16

typedef _Float16 v8h __attribute__((ext_vector_type(8)));
typedef _Float16 v4h __attribute__((ext_vector_type(4)));
typedef __fp16   f16x2 __attribute__((ext_vector_type(2)));
typedef float    v4f __attribute__((ext_vector_type(4)));

// ws layout (floats):
//  BAR_OFF  [0, 1024)         per-batch barrier counters, 32 dwords (128B) apart
//                             (zeroed by hipMemsetAsync before each launch)
//  PART_OFF [2048, ...)       partial Kabsch sums [ITERS][BN][8][8]
#define BAR_OFF  0
#define PART_OFF 2048

// Closed-form 2x2 Kabsch from summed acc (a8[8]); composes onto (c,s,tx,ty).
__device__ __forceinline__ void kabsch_compose(const float* a8,
                                               float& Tc, float& Ts,
                                               float& Ttx, float& Tty) {
    const float Ssx = a8[0], Ssy = a8[1], Stcx = a8[2], Stcy = a8[3];
    const float Sxx = a8[4], Sxy = a8[5], Syx = a8[6], Syy = a8[7];
    const float invN = 1.0f / (float)NPTS;
    const float csx = Ssx * invN, csy = Ssy * invN;
    const float ctx = Stcx * invN, cty = Stcy * invN;
    const float Hxx = Sxx - Ssx * ctx;
    const float Hxy = Sxy - Ssx * cty;
    const float Hyx = Syx - Ssy * ctx;
    const float Hyy = Syy - Ssy * cty;
    // A = H^T ; R_delta = polar(A) = V U^T
    const float a = Hxx, bb = Hyx, cc = Hxy, d = Hyy;
    const float det = a * d - bb * cc;
    const bool refl = (det < 0.f);
    const float xr = refl ? (a - d) : (a + d);
    const float yr = refl ? (bb + cc) : (cc - bb);
    const float r = fmaxf(sqrtf(xr * xr + yr * yr), 1e-30f);
    const float R00 = xr / r, R10 = yr / r;
    const float R01 = refl ? R10 : -R10;
    const float R11 = refl ? -R00 : R00;
    const float tdx = ctx - (R00 * csx + R01 * csy);
    const float tdy = cty - (R10 * csx + R11 * csy);
    const float cD = R00, sD = R10;      // cos/sin(delta_theta)
    const float nC  = cD * Tc - sD * Ts;
    const float nS  = sD * Tc + cD * Ts;
    const float nTx = cD * Ttx - sD * Tty + tdx;
    const float nTy = sD * Ttx + cD * Tty + tdy;
    Tc = nC; Ts = nS; Ttx = nTx; Tty = nTy;
}

// Per-batch 8-block barrier: monotonic counter per batch on its own 128B
// line; iter k waits for count >= 8*(k+1); no per-iter reset. Release-add /
// acquire-load makes the 8 blocks' relaxed partial stores visible.
__device__ __forceinline__ void batch_sync(unsigned* cnt, int tid, unsigned target) {
    __syncthreads();
    if (tid == 0) {
        __hip_atomic_fetch_add(cnt, 1u, __ATOMIC_RELEASE, __HIP_MEMORY_SCOPE_AGENT);
        unsigned v;
        do {
            __builtin_amdgcn_s_sleep(1);
            v = __hip_atomic_load(cnt, __ATOMIC_ACQUIRE, __HIP_MEMORY_SCOPE_AGENT);
        } while (v < target);
    }
    __syncthreads();
}

// ---------------------------------------------------------------------------
// Fused persistent ICP, 512-thread blocks. R6 post-mortem: the register budget
// on gfx950 is TOTAL (VGPR+AGPR unified) = 512 / waves_per_EU. A 1024-thread
// block (16 waves) forces >=4 waves/EU -> 128 regs/wave; the ~160-dword
// pipeline then spills ~32 dwords/thread (the invariant 33MB write signature
// of R1/R2/R5; R6's (1024,8) made it 64 regs -> 86MB+198MB). NO 1024-thread
// shape can fit. Fix: 512-thread blocks (8 waves) at 1 block/CU = 2 waves/EU
// -> 256 regs/wave, zero spill. Each wave owns an m-HALF (64 tiles, was 32);
// block still covers 256 rows x 2048 targets; grid still 256 blocks.
// Co-residency for the spin barrier: >128 regs/wave means only 1 block/CU
// fits -> 256 blocks on 256 CUs, all resident by construction.
// Per tile: D1 = mfma_16x16x32_f16(a1, B1[nt], 0)   // scores (fp32)
//           P  = pkrtz(exp2(D1))                     // f16; D-layout==B-layout
//           D2 = mfma_16x16x16_f16(a2, P, D2)        // rows 0..2 = den, ax, ay
// ---------------------------------------------------------------------------
__global__ __launch_bounds__(512, 2)
void icp_fused(const float* __restrict__ source,
               const float* __restrict__ target,
               const float* __restrict__ init_t,
               float* __restrict__ ws,
               float* __restrict__ out) {
    __shared__ v8h A1s[2050];            // 2048 payload + [2048]=const11 [2049]=zero
    __shared__ v8h A2s[516];             // 512 payload + [512]=ones4 [513]=zero
    __shared__ float4 comb[8][4][16];
    __shared__ float red[4][8];
    __shared__ float shT[6];
    __shared__ float pacc[64];
    const int tid = threadIdx.x;
    const int wv  = tid >> 6;            // 0..7
    const int l   = tid & 63;
    const int q   = l >> 4;
    const int col = l & 15;
    const int wh  = wv & 1;              // m-half (64 tiles each)
    const int rg  = wv >> 1;             // row-group within block (0..3)
    const int b   = blockIdx.x & 31;     // batch
    const int gg  = blockIdx.x >> 5;     // 256-row group (0..7)
    const int g   = gg * 4 + rg;         // 64-row group (0..31)

    unsigned* bar = (unsigned*)(ws + BAR_OFF) + b * 32;   // 128B line per batch

    const _Float16 h0 = (_Float16)0.0f;
    const _Float16 h1 = (_Float16)1.0f;

    // ---- build LDS payloads directly from target (ONCE per CU) ----
    const float2* tg = (const float2*)target + b * MPTS;
#pragma unroll
    for (int i = 0; i < 4; ++i) {
        const int m = tid + i * 512;
        const float2 k = tg[m];
        const float bm = -LOG2E * fmaf(k.x, k.x, k.y * k.y);
        const _Float16 kxh = (_Float16)k.x;
        const _Float16 kxl = (_Float16)(k.x - (float)kxh);
        const _Float16 kyh = (_Float16)k.y;
        const _Float16 kyl = (_Float16)(k.y - (float)kyh);
        const _Float16 bmh = (_Float16)bm;
        const _Float16 bml = (_Float16)(bm - (float)bmh);
        A1s[m] = (v8h){kxh, kxh, kxl, kyh, kyh, kyl, bmh, bml};
    }
    {                                    // A2: entry e holds kx/ky of targets 4e..4e+3
        const int e = tid;
        const float2 k0 = tg[e * 4 + 0];
        const float2 k1 = tg[e * 4 + 1];
        const float2 k2 = tg[e * 4 + 2];
        const float2 k3 = tg[e * 4 + 3];
        A2s[e] = (v8h){(_Float16)k0.x, (_Float16)k1.x, (_Float16)k2.x, (_Float16)k3.x,
                       (_Float16)k0.y, (_Float16)k1.y, (_Float16)k2.y, (_Float16)k3.y};
    }
    if (tid == 0) {
        A1s[2048] = (v8h){h1, h1, h0, h0, h0, h0, h0, h0};
        A1s[2049] = (v8h){h0, h0, h0, h0, h0, h0, h0, h0};
        A2s[512]  = (v8h){h1, h1, h1, h1, h0, h0, h0, h0};
        A2s[513]  = (v8h){h0, h0, h0, h0, h0, h0, h0, h0};
        // initial T from init vector
        const float th = init_t[b * 3 + 0];
        const float c = cosf(th), s = sinf(th);
        shT[0] = c; shT[1] = -s; shT[2] = init_t[b * 3 + 1];
        shT[3] = s; shT[4] = c;  shT[5] = init_t[b * 3 + 2];
    }
    __syncthreads();

    // ---- per-lane LDS addressing constants ----
    const char* A1c = (const char*)A1s;
    const char* A2c = (const char*)A2s;
    const int ad1_0 = (q == 0) ? (wh * 1024 + col) * 16 : ((q == 1) ? 2048 * 16 : 2049 * 16);
    const int st1   = (q == 0) ? 256 : 0;
    const int ad2_0 = (col == 1) ? (wh * 4096 + q * 16)
                    : (col == 2) ? (wh * 4096 + q * 16 + 8)
                    : ((col == 0) ? 512 * 16 : 513 * 16);
    const int st2   = (col == 1 || col == 2) ? 64 : 0;
    const v4f zero4 = (v4f){0.f, 0.f, 0.f, 0.f};

#pragma unroll 1
    for (int iter = 0; iter < ITERS; ++iter) {
        const float r00 = shT[0], r01 = shT[1], tx = shT[2];
        const float r10 = shT[3], r11 = shT[4], ty = shT[5];

        // ---- B1 frags for this wave's 4 n-tiles ----
        v8h B1[4];
#pragma unroll
        for (int nt = 0; nt < 4; ++nt) {
            const int row = g * 64 + nt * 16 + col;
            const float2 sp = ((const float2*)source)[b * NPTS + row];
            const float sx = fmaf(r00, sp.x, fmaf(r01, sp.y, tx));
            const float sy = fmaf(r10, sp.x, fmaf(r11, sp.y, ty));
            const float qpx = 2.0f * LOG2E * sx;
            const float qpy = 2.0f * LOG2E * sy;
            const float rc  = SHIFT_C - LOG2E * fmaf(sx, sx, sy * sy);
            const _Float16 qpxh = (_Float16)qpx;
            const _Float16 qpxl = (_Float16)(qpx - (float)qpxh);
            const _Float16 qpyh = (_Float16)qpy;
            const _Float16 qpyl = (_Float16)(qpy - (float)qpyh);
            const _Float16 rch  = (_Float16)rc;
            const _Float16 rcl  = (_Float16)(rc - (float)rch);
            v8h f;
            if (q == 0)      f = (v8h){qpxh, qpxl, qpxh, qpyh, qpyl, qpyh, h1, h1};
            else if (q == 1) f = (v8h){rch, rcl, h0, h0, h0, h0, h0, h0};
            else             f = (v8h){h0, h0, h0, h0, h0, h0, h0, h0};
            B1[nt] = f;
        }

        int ad1 = ad1_0;
        int ad2 = ad2_0;

        v4f D2[4];
#pragma unroll
        for (int nt = 0; nt < 4; ++nt) D2[nt] = zero4;

        // ---- fully-unrolled 64-tile pipeline, depth-limited circular bufs ----
        v8h a1w[4];                      // slots (t)&3; load t+2, consume t+1 (D1), t (D2 path)
        v4h a2w[4];
        v4f D1w[2][4];                   // slots (t)&1; produce t+1, consume t
        a1w[0] = *(const v8h*)(A1c + ad1); a2w[0] = *(const v4h*)(A2c + ad2);
        ad1 += st1; ad2 += st2;
        a1w[1] = *(const v8h*)(A1c + ad1); a2w[1] = *(const v4h*)(A2c + ad2);
        ad1 += st1; ad2 += st2;
#pragma unroll
        for (int nt = 0; nt < 4; ++nt)
            D1w[0][nt] = __builtin_amdgcn_mfma_f32_16x16x32_f16(a1w[0], B1[nt], zero4, 0, 0, 0);

#pragma unroll
        for (int t = 0; t < 64; ++t) {
            if (t < 62) {                        // ds prefetch depth 2
                a1w[(t + 2) & 3] = *(const v8h*)(A1c + ad1);
                a2w[(t + 2) & 3] = *(const v4h*)(A2c + ad2);
                ad1 += st1; ad2 += st2;
            }
            if (t < 63) {                        // score tile t+1 ahead of consuming t
#pragma unroll
                for (int nt = 0; nt < 4; ++nt)
                    D1w[(t + 1) & 1][nt] =
                        __builtin_amdgcn_mfma_f32_16x16x32_f16(a1w[(t + 1) & 3], B1[nt], zero4, 0, 0, 0);
            }
            // consume tile t: 16 exps batched, then pack + accumulate
            float e[16];
#pragma unroll
            for (int nt = 0; nt < 4; ++nt)
#pragma unroll
                for (int j = 0; j < 4; ++j)
                    e[nt * 4 + j] = __builtin_amdgcn_exp2f(D1w[t & 1][nt][j]);
#pragma unroll
            for (int nt = 0; nt < 4; ++nt) {
                union { v4h v; f16x2 h[2]; } u;
                u.h[0] = __builtin_amdgcn_cvt_pkrtz(e[nt * 4 + 0], e[nt * 4 + 1]);
                u.h[1] = __builtin_amdgcn_cvt_pkrtz(e[nt * 4 + 2], e[nt * 4 + 3]);
                D2[nt] = __builtin_amdgcn_mfma_f32_16x16x16f16(a2w[t & 3], u.v, D2[nt], 0, 0, 0);
            }
        }

        // ---- combine the 2 m-halves within each row-group ----
        if (l < 16) {
#pragma unroll
            for (int nt = 0; nt < 4; ++nt)
                comb[wv][nt][col] = make_float4(D2[nt][0], D2[nt][1], D2[nt][2], 0.f);
        }
        __syncthreads();
        float den = 0.f, ax = 0.f, ay = 0.f;
#pragma unroll
        for (int w = 0; w < 2; ++w) {
            const float4 p = comb[rg * 2 + w][q][col];
            den += p.x; ax += p.y; ay += p.z;
        }
        const float tcx = ax / den;
        const float tcy = ay / den;
        const int erow = g * 64 + q * 16 + col;
        const float2 sp = ((const float2*)source)[b * NPTS + erow];
        const float sx = fmaf(r00, sp.x, fmaf(r01, sp.y, tx));
        const float sy = fmaf(r10, sp.x, fmaf(r11, sp.y, ty));
        float v[8] = {sx, sy, tcx, tcy, sx * tcx, sx * tcy, sy * tcx, sy * tcy};
#pragma unroll
        for (int off = 32; off > 0; off >>= 1) {
#pragma unroll
            for (int j = 0; j < 8; ++j) v[j] += __shfl_xor(v[j], off, 64);
        }
        if (l == 0 && wh == 0) {                 // wv = rg*2: one writer per row-group
#pragma unroll
            for (int j = 0; j < 8; ++j) red[rg][j] = v[j];
        }
        __syncthreads();
        if (tid < 8) {                           // block's slot: agent-scope (cross-XCD) stores
            const float vsum = (red[0][tid] + red[1][tid]) + (red[2][tid] + red[3][tid]);
            __hip_atomic_store(ws + PART_OFF + (size_t)iter * BN * 64 + b * 64 + gg * 8 + tid,
                               vsum, __ATOMIC_RELAXED, __HIP_MEMORY_SCOPE_AGENT);
        }

        batch_sync(bar, tid, 8u * (unsigned)(iter + 1));   // this batch's 8 blocks only

        if (tid < 64)                            // load all 8 gg-slots for this batch
            pacc[tid] = __hip_atomic_load(ws + PART_OFF + (size_t)iter * BN * 64 + b * 64 + tid,
                                          __ATOMIC_ACQUIRE, __HIP_MEMORY_SCOPE_AGENT);
        __syncthreads();
        if (tid == 0) {
            float a8[8];
#pragma unroll
            for (int j = 0; j < 8; ++j) {
                float s = 0.f;
#pragma unroll
                for (int s8 = 0; s8 < 8; ++s8) s += pacc[s8 * 8 + j];
                a8[j] = s;
            }
            float Tc = shT[0], Ts = shT[3], Ttx = shT[2], Tty = shT[5];
            kabsch_compose(a8, Tc, Ts, Ttx, Tty);
            shT[0] = Tc; shT[1] = -Ts; shT[2] = Ttx;
            shT[3] = Ts; shT[4] = Tc;  shT[5] = Tty;
            if (iter == ITERS - 1 && gg == 0) {  // one writer block per batch
                out[b * 3 + 0] = atan2f(Ts, Tc);
                out[b * 3 + 1] = Ttx;
                out[b * 3 + 2] = Tty;
            }
        }
        __syncthreads();
    }
}

extern "C" void kernel_launch(void* const* d_in, const int* in_sizes, int n_in,
                              void* d_out, int out_size, void* d_ws, size_t ws_size,
                              hipStream_t stream) {
    const float* source = (const float*)d_in[0];
    const float* target = (const float*)d_in[1];
    const float* initt  = (const float*)d_in[2];
    float* out = (float*)d_out;
    float* ws  = (float*)d_ws;

    // zero the per-batch barrier counters (stream-ordered, graph-capture-safe)
    (void)hipMemsetAsync(ws + BAR_OFF, 0, 32 * 32 * sizeof(float), stream);

    icp_fused<<<dim3(BN * 8), dim3(512), 0, stream>>>(source, target, initt, ws, out);
}